// Round 1
// baseline (764.272 us; speedup 1.0000x reference)
//
#include <hip/hip_runtime.h>
#include <math.h>

// SpectralConvLayer: spd[b,o,i,j] = sum_{c,n,d} u[c,n,i,d] * D[b,c,n,d]*|w[d,c,n,o]| * u[c,n,j,d]
// where u = left singular vectors of C[c,n] (descending s) = eigenvectors of C C^T (descending lambda).
// Signs of u columns cancel (u_id * u_jd), so a symmetric eigensolver + descending sort suffices.
//
// B=32, CENT=2, IN_CH=8 (cn=16 matrices), OUT_CH=16, NDIAG=64.

#define NSWEEP 12

// ---------------- Kernel 1: batched 64x64 symmetric Jacobi eigensolver ----------------
// 16 blocks (one per (c,n) matrix), 512 threads.
// ws layout: ut[cn][d][i] = u[c,n,i,d] (d = sorted-descending eigen index), 16*64*64 floats.
__global__ __launch_bounds__(512) void eig_kernel(const float* __restrict__ C,
                                                  float* __restrict__ ut) {
    __shared__ float A[64][65];   // padded: bank-conflict-free column walks
    __shared__ float V[64][65];
    __shared__ float Cs[64][65];
    __shared__ float pc[32], ps[32];
    __shared__ int   pp_[32], pq_[32];
    __shared__ float lam[64];

    const int mat = blockIdx.x;         // cn = c*8+n
    const int tid = threadIdx.x;
    const float* Cm = C + mat * 4096;

    // load C tile
    for (int idx = tid; idx < 4096; idx += 512)
        Cs[idx >> 6][idx & 63] = Cm[idx];
    __syncthreads();

    // A = C C^T ; V = I
    for (int idx = tid; idx < 4096; idx += 512) {
        int i = idx >> 6, j = idx & 63;
        float s = 0.f;
        #pragma unroll 8
        for (int k = 0; k < 64; k++) s += Cs[i][k] * Cs[j][k];
        A[i][j] = s;
        V[i][j] = (i == j) ? 1.f : 0.f;
    }
    __syncthreads();

    // Parallel two-sided Jacobi: tournament schedule, 32 disjoint pairs per round.
    for (int sweep = 0; sweep < NSWEEP; sweep++) {
        for (int r = 0; r < 63; r++) {
            // phase 0: rotation angles (GVL sym.schur2 convention)
            if (tid < 32) {
                int p, q;
                if (tid == 0) { p = 63; q = r; }
                else { p = (r + tid) % 63; q = (r - tid + 63) % 63; }
                float app = A[p][p], aqq = A[q][q], apq = A[p][q];
                float c = 1.f, s = 0.f;
                if (fabsf(apq) > 1e-12f) {
                    float tau = (aqq - app) / (2.f * apq);
                    float t = copysignf(1.f, tau) / (fabsf(tau) + sqrtf(1.f + tau * tau));
                    c = 1.f / sqrtf(1.f + t * t);
                    s = t * c;
                }
                pp_[tid] = p; pq_[tid] = q; pc[tid] = c; ps[tid] = s;
            }
            __syncthreads();
            // phase 1: A <- J^T A J as 1024 independent 2x2 block updates (2 per thread),
            // each element read+written exactly once. Plus V <- V J column rotations.
            #pragma unroll
            for (int bi = 0; bi < 2; bi++) {
                int blk = tid + bi * 512;
                int kr = blk >> 5, kc = blk & 31;
                int p = pp_[kr], q = pq_[kr];
                int rr = pp_[kc], ss = pq_[kc];
                float c1 = pc[kr], s1 = ps[kr];
                float c2 = pc[kc], s2 = ps[kc];
                float a = A[p][rr], b = A[p][ss], cq = A[q][rr], d = A[q][ss];
                // row rotation (J^T on left)
                float ra = c1 * a - s1 * cq, rb = c1 * b - s1 * d;
                float rc = s1 * a + c1 * cq, rd = s1 * b + c1 * d;
                // col rotation (J on right)
                A[p][rr] = c2 * ra - s2 * rb;
                A[p][ss] = s2 * ra + c2 * rb;
                A[q][rr] = c2 * rc - s2 * rd;
                A[q][ss] = s2 * rc + c2 * rd;
            }
            {
                int kc = tid >> 4;           // pair 0..31
                int i0 = (tid & 15) * 4;     // 4 rows each
                int rr = pp_[kc], ss = pq_[kc];
                float c2 = pc[kc], s2 = ps[kc];
                #pragma unroll
                for (int i = i0; i < i0 + 4; i++) {
                    float vp = V[i][rr], vq = V[i][ss];
                    V[i][rr] = c2 * vp - s2 * vq;
                    V[i][ss] = s2 * vp + c2 * vq;
                }
            }
            __syncthreads();
        }
    }

    // sort eigenpairs descending, write ut[mat][rank][i] = V[i][k]
    if (tid < 64) lam[tid] = A[tid][tid];
    __syncthreads();
    if (tid < 256) {
        int k = tid & 63, quarter = tid >> 6;
        float lk = lam[k];
        int rank = 0;
        #pragma unroll 8
        for (int e = 0; e < 64; e++) {
            float le = lam[e];
            rank += (le > lk) || (le == lk && e < k);
        }
        float* dst = ut + (mat * 64 + rank) * 64;
        for (int i = quarter * 16; i < quarter * 16 + 16; i++)
            dst[i] = V[i][k];
    }
}

// ---------------- Kernel 2: spd accumulation ----------------
// grid 512 = (b,o); 256 threads; each thread owns a 4x4 output tile of the 64x64 (i,j) plane.
__global__ __launch_bounds__(256) void spd_kernel(const float* __restrict__ D,
                                                  const float* __restrict__ w,
                                                  const float* __restrict__ ut,
                                                  float* __restrict__ out) {
    __shared__ __align__(16) float U[64][64];   // U[d][i]
    __shared__ float t[64];

    const int bid = blockIdx.x;
    const int b = bid >> 4, o = bid & 15;
    const int tid = threadIdx.x;
    const int ti = tid & 15, tj = tid >> 4;

    float acc[4][4] = {{0.f, 0.f, 0.f, 0.f}, {0.f, 0.f, 0.f, 0.f},
                       {0.f, 0.f, 0.f, 0.f}, {0.f, 0.f, 0.f, 0.f}};

    for (int cn = 0; cn < 16; cn++) {
        __syncthreads();   // protect U/t from previous iteration's readers
        // stage ut[cn] (16 KB) into LDS
        const float4* src = (const float4*)(ut + cn * 4096);
        float4* dstU = (float4*)(&U[0][0]);
        #pragma unroll
        for (int idx = tid; idx < 1024; idx += 256) dstU[idx] = src[idx];
        // per-(b,o,cn) diagonal weights t[d] = D[b,cn,d] * |w[d,cn,o]|
        if (tid < 64) {
            int d = tid;
            float dv = D[(b * 16 + cn) * 64 + d];
            float wv = fabsf(w[(d * 16 + cn) * 16 + o]);
            t[d] = dv * wv;
        }
        __syncthreads();

        #pragma unroll 4
        for (int d = 0; d < 64; d++) {
            float td = t[d];
            float4 uiv = *(const float4*)(&U[d][ti * 4]);
            float4 ujv = *(const float4*)(&U[d][tj * 4]);
            float si0 = td * uiv.x, si1 = td * uiv.y, si2 = td * uiv.z, si3 = td * uiv.w;
            acc[0][0] += si0 * ujv.x; acc[0][1] += si0 * ujv.y; acc[0][2] += si0 * ujv.z; acc[0][3] += si0 * ujv.w;
            acc[1][0] += si1 * ujv.x; acc[1][1] += si1 * ujv.y; acc[1][2] += si1 * ujv.z; acc[1][3] += si1 * ujv.w;
            acc[2][0] += si2 * ujv.x; acc[2][1] += si2 * ujv.y; acc[2][2] += si2 * ujv.z; acc[2][3] += si2 * ujv.w;
            acc[3][0] += si3 * ujv.x; acc[3][1] += si3 * ujv.y; acc[3][2] += si3 * ujv.z; acc[3][3] += si3 * ujv.w;
        }
    }

    // out[b][o][i][j], i = ti*4+k, j = tj*4..+3 — float4 stores
    float* obase = out + (size_t)bid * 4096;
    #pragma unroll
    for (int k = 0; k < 4; k++) {
        float4 v = make_float4(acc[k][0], acc[k][1], acc[k][2], acc[k][3]);
        *(float4*)(&obase[(ti * 4 + k) * 64 + tj * 4]) = v;
    }
}

extern "C" void kernel_launch(void* const* d_in, const int* in_sizes, int n_in,
                              void* d_out, int out_size, void* d_ws, size_t ws_size,
                              hipStream_t stream) {
    const float* D = (const float*)d_in[0];   // (32,2,8,64)
    const float* C = (const float*)d_in[1];   // (2,8,64,64)
    const float* w = (const float*)d_in[2];   // (64,2,8,16)
    float* out = (float*)d_out;               // (32,16,64,64)
    float* ut  = (float*)d_ws;                // 16*64*64 floats = 256 KB

    hipLaunchKernelGGL(eig_kernel, dim3(16), dim3(512), 0, stream, C, ut);
    hipLaunchKernelGGL(spd_kernel, dim3(512), dim3(256), 0, stream, D, w, ut, out);
}

// Round 2
// 556.629 us; speedup vs baseline: 1.3730x; 1.3730x over previous
//
#include <hip/hip_runtime.h>
#include <math.h>

// SpectralConvLayer: spd[b,o,i,j] = sum_{c,n,d} u[c,n,i,d] * D[b,c,n,d]*|w[d,c,n,o]| * u[c,n,j,d]
// u = left singular vectors of C[c,n], descending sigma. Column signs cancel (u_id*u_jd).
//
// Kernel 1: register-resident ONE-SIDED Jacobi (Hestenes) on C's columns.
//   C*V = U*Sigma at convergence -> u_k = g_k / ||g_k||, ranked by descending ||g_k||.
//   One wave per matrix; lane j owns column j in 64 VGPRs. XOR pair schedule m=1..63
//   (32 disjoint pairs/round, all 2016 pairs/sweep). Partner column via ds_bpermute
//   (64 instr/round = minimum possible cross-lane traffic). No LDS arrays, no barriers.
//
// B=32, CENT=2, IN_CH=8 (16 matrices), OUT_CH=16, NDIAG=64.

#define NSWEEP 9

__global__ __launch_bounds__(64) void eig_kernel(const float* __restrict__ C,
                                                 float* __restrict__ ut) {
    const int mat  = blockIdx.x;          // cn
    const int lane = threadIdx.x;         // 0..63, owns column `lane`
    const float* Cm = C + mat * 4096;

    // load column: g[i] = C[mat][i][lane]  (coalesced per i)
    float g[64];
    #pragma unroll
    for (int i = 0; i < 64; i++) g[i] = Cm[i * 64 + lane];

    // initial squared norm (maintained analytically during sweeps)
    float nrm;
    {
        float n0 = 0.f, n1 = 0.f, n2 = 0.f, n3 = 0.f;
        #pragma unroll
        for (int i = 0; i < 64; i += 4) {
            n0 = fmaf(g[i],     g[i],     n0);
            n1 = fmaf(g[i + 1], g[i + 1], n1);
            n2 = fmaf(g[i + 2], g[i + 2], n2);
            n3 = fmaf(g[i + 3], g[i + 3], n3);
        }
        nrm = (n0 + n1) + (n2 + n3);
    }

    for (int sweep = 0; sweep < NSWEEP; sweep++) {
        for (int m = 1; m < 64; m++) {
            const int partner = lane ^ m;
            const int paddr   = partner << 2;

            // fetch partner column + partner norm (pre-rotation values)
            float tmp[64];
            #pragma unroll
            for (int i = 0; i < 64; i++)
                tmp[i] = __int_as_float(__builtin_amdgcn_ds_bpermute(paddr, __float_as_int(g[i])));
            float pn = __int_as_float(__builtin_amdgcn_ds_bpermute(paddr, __float_as_int(nrm)));

            // gamma = g_p . g_q  (bit-identical on both lanes of the pair: same order)
            float d0 = 0.f, d1 = 0.f, d2 = 0.f, d3 = 0.f;
            #pragma unroll
            for (int i = 0; i < 64; i += 4) {
                d0 = fmaf(g[i],     tmp[i],     d0);
                d1 = fmaf(g[i + 1], tmp[i + 1], d1);
                d2 = fmaf(g[i + 2], tmp[i + 2], d2);
                d3 = fmaf(g[i + 3], tmp[i + 3], d3);
            }
            const float gam = (d0 + d1) + (d2 + d3);

            // rotation zeroing the pair's off-diagonal of the implicit Gram matrix.
            // zeta = (nqq - npp)/(2 gamma); p = lower lane of the pair.
            const bool  is_p = lane < partner;
            const float diff = pn - nrm;                    // lane p: nqq-npp; lane q: -(nqq-npp)
            const float zeta = (is_p ? diff : -diff) / (2.f * gam);
            float t0 = copysignf(1.f, zeta) / (fabsf(zeta) + sqrtf(fmaf(zeta, zeta, 1.f)));
            const float t = (fabsf(gam) > 1e-30f) ? t0 : 0.f;   // select kills inf/nan path
            const float c = rsqrtf(fmaf(t, t, 1.f));
            const float s = t * c;
            const float sa = is_p ? -s : s;                 // g'_p = c g_p - s g_q ; g'_q = s g_p + c g_q
            const float ta = is_p ? -t : t;                 // ||g'_p||^2 = npp - t*gam ; q: + t*gam

            #pragma unroll
            for (int i = 0; i < 64; i++)
                g[i] = fmaf(c, g[i], sa * tmp[i]);
            nrm = fmaf(ta, gam, nrm);
        }
    }

    // exact final norm (analytic update drifts slightly over 567 rounds)
    {
        float n0 = 0.f, n1 = 0.f, n2 = 0.f, n3 = 0.f;
        #pragma unroll
        for (int i = 0; i < 64; i += 4) {
            n0 = fmaf(g[i],     g[i],     n0);
            n1 = fmaf(g[i + 1], g[i + 1], n1);
            n2 = fmaf(g[i + 2], g[i + 2], n2);
            n3 = fmaf(g[i + 3], g[i + 3], n3);
        }
        nrm = (n0 + n1) + (n2 + n3);
    }

    // rank columns by descending sigma^2 (= nrm), index tiebreak
    __shared__ float sn[64];
    sn[lane] = nrm;
    __syncthreads();
    int rank = 0;
    #pragma unroll
    for (int e = 0; e < 64; e++) {
        float ne = sn[e];
        rank += (ne > nrm) || (ne == nrm && e < lane);
    }

    // write ut[mat][rank][i] = g[i]/sigma  (scattered; 16 KB/matrix, one-time)
    const float inv = rsqrtf(fmaxf(nrm, 1e-30f));
    float* dst = ut + (mat * 64 + rank) * 64;
    #pragma unroll
    for (int i = 0; i < 64; i++) dst[i] = g[i] * inv;
}

// ---------------- Kernel 2: spd accumulation (119 TF fp32, ~76% of vector peak) ----------------
__global__ __launch_bounds__(256) void spd_kernel(const float* __restrict__ D,
                                                  const float* __restrict__ w,
                                                  const float* __restrict__ ut,
                                                  float* __restrict__ out) {
    __shared__ __align__(16) float U[64][64];   // U[d][i]
    __shared__ float t[64];

    const int bid = blockIdx.x;
    const int b = bid >> 4, o = bid & 15;
    const int tid = threadIdx.x;
    const int ti = tid & 15, tj = tid >> 4;

    float acc[4][4] = {{0.f, 0.f, 0.f, 0.f}, {0.f, 0.f, 0.f, 0.f},
                       {0.f, 0.f, 0.f, 0.f}, {0.f, 0.f, 0.f, 0.f}};

    for (int cn = 0; cn < 16; cn++) {
        __syncthreads();   // protect U/t from previous iteration's readers
        const float4* src = (const float4*)(ut + cn * 4096);
        float4* dstU = (float4*)(&U[0][0]);
        #pragma unroll
        for (int idx = tid; idx < 1024; idx += 256) dstU[idx] = src[idx];
        if (tid < 64) {
            int d = tid;
            float dv = D[(b * 16 + cn) * 64 + d];
            float wv = fabsf(w[(d * 16 + cn) * 16 + o]);
            t[d] = dv * wv;
        }
        __syncthreads();

        #pragma unroll 4
        for (int d = 0; d < 64; d++) {
            float td = t[d];
            float4 uiv = *(const float4*)(&U[d][ti * 4]);
            float4 ujv = *(const float4*)(&U[d][tj * 4]);
            float si0 = td * uiv.x, si1 = td * uiv.y, si2 = td * uiv.z, si3 = td * uiv.w;
            acc[0][0] += si0 * ujv.x; acc[0][1] += si0 * ujv.y; acc[0][2] += si0 * ujv.z; acc[0][3] += si0 * ujv.w;
            acc[1][0] += si1 * ujv.x; acc[1][1] += si1 * ujv.y; acc[1][2] += si1 * ujv.z; acc[1][3] += si1 * ujv.w;
            acc[2][0] += si2 * ujv.x; acc[2][1] += si2 * ujv.y; acc[2][2] += si2 * ujv.z; acc[2][3] += si2 * ujv.w;
            acc[3][0] += si3 * ujv.x; acc[3][1] += si3 * ujv.y; acc[3][2] += si3 * ujv.z; acc[3][3] += si3 * ujv.w;
        }
    }

    float* obase = out + (size_t)bid * 4096;
    #pragma unroll
    for (int k = 0; k < 4; k++) {
        float4 v = make_float4(acc[k][0], acc[k][1], acc[k][2], acc[k][3]);
        *(float4*)(&obase[(ti * 4 + k) * 64 + tj * 4]) = v;
    }
}

extern "C" void kernel_launch(void* const* d_in, const int* in_sizes, int n_in,
                              void* d_out, int out_size, void* d_ws, size_t ws_size,
                              hipStream_t stream) {
    const float* D = (const float*)d_in[0];   // (32,2,8,64)
    const float* C = (const float*)d_in[1];   // (2,8,64,64)
    const float* w = (const float*)d_in[2];   // (64,2,8,16)
    float* out = (float*)d_out;               // (32,16,64,64)
    float* ut  = (float*)d_ws;                // 16*64*64 floats = 256 KB

    hipLaunchKernelGGL(eig_kernel, dim3(16), dim3(64), 0, stream, C, ut);
    hipLaunchKernelGGL(spd_kernel, dim3(512), dim3(256), 0, stream, D, w, ut, out);
}

// Round 3
// 327.438 us; speedup vs baseline: 2.3341x; 1.7000x over previous
//
#include <hip/hip_runtime.h>
#include <math.h>

// SpectralConvLayer: spd[b,o,i,j] = sum_{c,n,d} u[c,n,i,d] * D[b,c,n,d]*|w[d,c,n,o]| * u[c,n,j,d]
// u = left singular vectors of C[c,n] (descending sigma); column signs cancel.
//
// eig: one-sided Jacobi (Hestenes) on C's columns, 2 waves per matrix.
//   Wave w holds rows [32w,32w+32) of all 64 columns; lane j owns column j's half.
//   XOR pair schedule m=1..63. Partner half-column via ds_bpermute (in-wave).
//   Cross-wave: only the partial dot product, via parity-double-buffered LDS + 1 barrier/round.
//   Software pipeline: round r's column update is fused with round r+1's bpermute fetch.
//
// B=32, CENT=2, IN_CH=8 (16 matrices), OUT_CH=16, NDIAG=64.

#define NSWEEP 8
#define NROUND (NSWEEP * 63)   // 504, even (required by the unroll-by-2 pipeline)

__device__ __forceinline__ float bper(int paddr, float v) {
    return __int_as_float(__builtin_amdgcn_ds_bpermute(paddr, __float_as_int(v)));
}

__device__ __forceinline__ float pdot32(const float (&a)[32], const float (&b)[32]) {
    float d0 = 0.f, d1 = 0.f, d2 = 0.f, d3 = 0.f;
    #pragma unroll
    for (int i = 0; i < 32; i += 4) {
        d0 = fmaf(a[i],     b[i],     d0);
        d1 = fmaf(a[i + 1], b[i + 1], d1);
        d2 = fmaf(a[i + 2], b[i + 2], d2);
        d3 = fmaf(a[i + 3], b[i + 3], d3);
    }
    return (d0 + d1) + (d2 + d3);
}

// One Jacobi round r: consume (tin, gam, pn) of round r, update g and nrm,
// then (unless last) fetch round r+1's partner half-column into tout and
// exchange partial dots -> (gam, pn) for round r+1.
__device__ __forceinline__ void round_body(
    float (&g)[32], float (&tin)[32], float (&tout)[32],
    float& nrm, float& gam, float& pn, int& m,
    const int lane, const int wv, float (&pex)[2][2][64],
    const int par_next, const bool last)
{
    const int partner = lane ^ m;
    const bool is_p = lane < partner;

    // rotation zeroing the implicit Gram off-diagonal for this pair
    const float diff = pn - nrm;                    // lane p: nqq-npp ; lane q: -(...)
    const float num  = is_p ? diff : -diff;
    const float zeta = num * 0.5f * __builtin_amdgcn_rcpf(gam);
    const float t0   = copysignf(1.f, zeta) *
                       __builtin_amdgcn_rcpf(fabsf(zeta) + sqrtf(fmaf(zeta, zeta, 1.f)));
    const float t    = (fabsf(gam) > 1e-30f) ? t0 : 0.f;   // select kills inf/nan path
    const float c    = __builtin_amdgcn_rsqf(fmaf(t, t, 1.f));
    const float s    = t * c;
    const float sa   = is_p ? -s : s;               // g'_p = c g_p - s g_q ; g'_q = s g_p + c g_q
    const float ta   = is_p ? -t : t;               // ||g'||^2 analytic update
    nrm = fmaf(ta, gam, nrm);

    m = (m == 63) ? 1 : m + 1;                      // next round's mask (wraps across sweeps)

    if (last) {
        #pragma unroll
        for (int i = 0; i < 32; i++) g[i] = fmaf(c, g[i], sa * tin[i]);
        return;
    }

    // fused: update round r + fetch round r+1 (bpermute latency hides under update issue)
    const int paddr = (lane ^ m) << 2;
    #pragma unroll
    for (int i = 0; i < 32; i++) {
        g[i]    = fmaf(c, g[i], sa * tin[i]);
        tout[i] = bper(paddr, g[i]);
    }
    pn = bper(paddr, nrm);

    // partial dot for round r+1, cross-wave exchange (one barrier per round)
    const float part = pdot32(g, tout);
    pex[par_next][wv][lane] = part;
    __syncthreads();
    gam = part + pex[par_next][wv ^ 1][lane];       // same two values both waves -> identical
}

__global__ __launch_bounds__(128, 1) void eig_kernel(const float* __restrict__ C,
                                                     float* __restrict__ ut) {
    __shared__ float pex[2][2][64];
    __shared__ float sn[64];

    const int mat  = blockIdx.x;          // cn
    const int tid  = threadIdx.x;
    const int wv   = tid >> 6;            // wave 0/1
    const int lane = tid & 63;            // owns column `lane`
    const int row0 = wv << 5;             // this wave's row half
    const float* Cm = C + mat * 4096;

    float g[32];
    #pragma unroll
    for (int i = 0; i < 32; i++) g[i] = Cm[(row0 + i) * 64 + lane];

    // initial full squared norm (partial + cross-wave exchange, slot 1)
    float nrm;
    {
        const float part = pdot32(g, g);
        pex[1][wv][lane] = part;
        __syncthreads();
        nrm = part + pex[1][wv ^ 1][lane];
    }

    float tA[32], tB[32];
    float gam, pn;
    int m = 1;

    // prologue: fetch round 0 (m=1), exchange partial dot via slot 0
    {
        const int paddr = (lane ^ 1) << 2;
        #pragma unroll
        for (int i = 0; i < 32; i++) tA[i] = bper(paddr, g[i]);
        pn = bper(paddr, nrm);
        const float part = pdot32(g, tA);
        pex[0][wv][lane] = part;
        __syncthreads();
        gam = part + pex[0][wv ^ 1][lane];
    }

    for (int r = 0; r < NROUND; r += 2) {
        round_body(g, tA, tB, nrm, gam, pn, m, lane, wv, pex, 1, false);
        round_body(g, tB, tA, nrm, gam, pn, m, lane, wv, pex, 0, r + 2 >= NROUND);
    }

    // exact final norm (analytic update drifts over 504 rounds)
    {
        const float part = pdot32(g, g);
        __syncthreads();                    // drain pending reads of pex slots
        pex[0][wv][lane] = part;
        __syncthreads();
        nrm = part + pex[0][wv ^ 1][lane];
    }

    // rank columns by descending sigma^2, index tiebreak
    if (wv == 0) sn[lane] = nrm;
    __syncthreads();
    int rank = 0;
    #pragma unroll 8
    for (int e = 0; e < 64; e++) {
        const float ne = sn[e];
        rank += (ne > nrm) || (ne == nrm && e < lane);
    }

    // ut[mat][rank][row] = g[row]/sigma
    const float inv = __builtin_amdgcn_rsqf(fmaxf(nrm, 1e-30f));
    float* dst = ut + (mat * 64 + rank) * 64 + row0;
    #pragma unroll
    for (int i = 0; i < 32; i++) dst[i] = g[i] * inv;
}

// ---------------- Kernel 2: spd accumulation (~119 TF fp32, ~76% of vector peak) ----------------
__global__ __launch_bounds__(256) void spd_kernel(const float* __restrict__ D,
                                                  const float* __restrict__ w,
                                                  const float* __restrict__ ut,
                                                  float* __restrict__ out) {
    __shared__ __align__(16) float U[64][64];   // U[d][i]
    __shared__ float t[64];

    const int bid = blockIdx.x;
    const int b = bid >> 4, o = bid & 15;
    const int tid = threadIdx.x;
    const int ti = tid & 15, tj = tid >> 4;

    float acc[4][4] = {{0.f, 0.f, 0.f, 0.f}, {0.f, 0.f, 0.f, 0.f},
                       {0.f, 0.f, 0.f, 0.f}, {0.f, 0.f, 0.f, 0.f}};

    for (int cn = 0; cn < 16; cn++) {
        __syncthreads();   // protect U/t from previous iteration's readers
        const float4* src = (const float4*)(ut + cn * 4096);
        float4* dstU = (float4*)(&U[0][0]);
        #pragma unroll
        for (int idx = tid; idx < 1024; idx += 256) dstU[idx] = src[idx];
        if (tid < 64) {
            int d = tid;
            float dv = D[(b * 16 + cn) * 64 + d];
            float wv = fabsf(w[(d * 16 + cn) * 16 + o]);
            t[d] = dv * wv;
        }
        __syncthreads();

        #pragma unroll 4
        for (int d = 0; d < 64; d++) {
            float td = t[d];
            float4 uiv = *(const float4*)(&U[d][ti * 4]);
            float4 ujv = *(const float4*)(&U[d][tj * 4]);
            float si0 = td * uiv.x, si1 = td * uiv.y, si2 = td * uiv.z, si3 = td * uiv.w;
            acc[0][0] += si0 * ujv.x; acc[0][1] += si0 * ujv.y; acc[0][2] += si0 * ujv.z; acc[0][3] += si0 * ujv.w;
            acc[1][0] += si1 * ujv.x; acc[1][1] += si1 * ujv.y; acc[1][2] += si1 * ujv.z; acc[1][3] += si1 * ujv.w;
            acc[2][0] += si2 * ujv.x; acc[2][1] += si2 * ujv.y; acc[2][2] += si2 * ujv.z; acc[2][3] += si2 * ujv.w;
            acc[3][0] += si3 * ujv.x; acc[3][1] += si3 * ujv.y; acc[3][2] += si3 * ujv.z; acc[3][3] += si3 * ujv.w;
        }
    }

    float* obase = out + (size_t)bid * 4096;
    #pragma unroll
    for (int k = 0; k < 4; k++) {
        float4 v = make_float4(acc[k][0], acc[k][1], acc[k][2], acc[k][3]);
        *(float4*)(&obase[(ti * 4 + k) * 64 + tj * 4]) = v;
    }
}

extern "C" void kernel_launch(void* const* d_in, const int* in_sizes, int n_in,
                              void* d_out, int out_size, void* d_ws, size_t ws_size,
                              hipStream_t stream) {
    const float* D = (const float*)d_in[0];   // (32,2,8,64)
    const float* C = (const float*)d_in[1];   // (2,8,64,64)
    const float* w = (const float*)d_in[2];   // (64,2,8,16)
    float* out = (float*)d_out;               // (32,16,64,64)
    float* ut  = (float*)d_ws;                // 16*64*64 floats = 256 KB

    hipLaunchKernelGGL(eig_kernel, dim3(16), dim3(128), 0, stream, C, ut);
    hipLaunchKernelGGL(spd_kernel, dim3(512), dim3(256), 0, stream, D, w, ut, out);
}

// Round 6
// 319.592 us; speedup vs baseline: 2.3914x; 1.0246x over previous
//
#include <hip/hip_runtime.h>
#include <math.h>

// SpectralConvLayer: spd[b,o,i,j] = sum_{c,n,d} u[c,n,i,d] * D[b,c,n,d]*|w[d,c,n,o]| * u[c,n,j,d]
// u = left singular vectors of C[c,n] (descending sigma); column signs cancel.
//
// eig: one-sided Jacobi (Hestenes) on C's columns, 4 waves per matrix, UNPIPELINED.
//   Wave w holds rows [16w,16w+16) of all 64 columns; lane j owns column j's quarter.
//   XOR pair schedule m=1..63. Per round: bpermute partner slice+norm -> partial dot
//   -> pex write -> BARRIER (RAW) -> canonical sum -> BARRIER (WAR) -> rotate in-register.
//   Single pex slot, two barriers: every cross-wave value crosses exactly one barrier
//   each way. (R4/R5's fused-pipeline 4-wave variant failed structurally — iteration-
//   count-independent absmax ~5.7; do NOT reintroduce it without a same-probe A/B.)
//
// NSWEEP=8: proven converged (absmax floor 0.0078) at 1-wave (R2) and 2-wave (R3).
//
// B=32, CENT=2, IN_CH=8 (16 matrices), OUT_CH=16, NDIAG=64.

#define NSWEEP 8
#define NROUND (NSWEEP * 63)   // 504

__device__ __forceinline__ float bper(int paddr, float v) {
    return __int_as_float(__builtin_amdgcn_ds_bpermute(paddr, __float_as_int(v)));
}

__device__ __forceinline__ float pdot16(const float (&a)[16], const float (&b)[16]) {
    float d0 = 0.f, d1 = 0.f, d2 = 0.f, d3 = 0.f;
    #pragma unroll
    for (int i = 0; i < 16; i += 4) {
        d0 = fmaf(a[i],     b[i],     d0);
        d1 = fmaf(a[i + 1], b[i + 1], d1);
        d2 = fmaf(a[i + 2], b[i + 2], d2);
        d3 = fmaf(a[i + 3], b[i + 3], d3);
    }
    return (d0 + d1) + (d2 + d3);
}

__global__ __launch_bounds__(256, 1) void eig_kernel(const float* __restrict__ C,
                                                     float* __restrict__ ut) {
    __shared__ float pex[4][64];
    __shared__ float sn[64];

    const int mat  = blockIdx.x;          // cn
    const int tid  = threadIdx.x;
    const int wv   = tid >> 6;            // wave 0..3
    const int lane = tid & 63;            // owns column `lane`
    const int row0 = wv << 4;             // this wave's row quarter
    const float* Cm = C + mat * 4096;

    float g[16];
    #pragma unroll
    for (int i = 0; i < 16; i++) g[i] = Cm[(row0 + i) * 64 + lane];

    // initial full squared norm: partials -> barrier -> canonical sum -> barrier
    float nrm;
    {
        pex[wv][lane] = pdot16(g, g);
        __syncthreads();
        nrm = (pex[0][lane] + pex[1][lane]) + (pex[2][lane] + pex[3][lane]);
        __syncthreads();
    }

    int m = 1;
    for (int r = 0; r < NROUND; ++r) {
        const int partner = lane ^ m;
        const int paddr   = partner << 2;

        // fetch partner quarter-column + partner norm (pre-rotation, lockstep in-wave)
        float tmp[16];
        #pragma unroll
        for (int i = 0; i < 16; i++) tmp[i] = bper(paddr, g[i]);
        const float pn = bper(paddr, nrm);

        // cross-wave exchange of the pair's dot product
        const float part = pdot16(g, tmp);
        pex[wv][lane] = part;
        __syncthreads();                                   // RAW: all partials visible
        const float gam = (pex[0][lane] + pex[1][lane]) + (pex[2][lane] + pex[3][lane]);
        __syncthreads();                                   // WAR: reads done before next write

        // rotation zeroing the implicit Gram off-diagonal (identical on all waves:
        // gam canonical, nrm replicated, pn = bper of replicated nrm)
        const bool  is_p = lane < partner;
        const float diff = pn - nrm;                       // p: nqq-npp ; q: -(...)
        const float num  = is_p ? diff : -diff;
        const float zeta = num * 0.5f * __builtin_amdgcn_rcpf(gam);
        const float t0   = copysignf(1.f, zeta) *
                           __builtin_amdgcn_rcpf(fabsf(zeta) + sqrtf(fmaf(zeta, zeta, 1.f)));
        const float t    = (fabsf(gam) > 1e-30f) ? t0 : 0.f;   // select kills inf/nan path
        const float c    = __builtin_amdgcn_rsqf(fmaf(t, t, 1.f));
        const float s    = t * c;
        const float sa   = is_p ? -s : s;                  // g'_p = c g_p - s g_q ; g'_q = s g_p + c g_q
        const float ta   = is_p ? -t : t;                  // analytic ||g'||^2 update

        #pragma unroll
        for (int i = 0; i < 16; i++) g[i] = fmaf(c, g[i], sa * tmp[i]);
        nrm = fmaf(ta, gam, nrm);

        m = (m == 63) ? 1 : m + 1;
    }

    // exact final norm (analytic update drifts over 504 rounds)
    {
        const float part = pdot16(g, g);
        pex[wv][lane] = part;          // safe: last round's reads closed by its 2nd barrier
        __syncthreads();
        nrm = (pex[0][lane] + pex[1][lane]) + (pex[2][lane] + pex[3][lane]);
    }

    // rank columns by descending sigma^2, index tiebreak (nrm replicated across waves)
    if (wv == 0) sn[lane] = nrm;
    __syncthreads();
    int rank = 0;
    #pragma unroll 8
    for (int e = 0; e < 64; e++) {
        const float ne = sn[e];
        rank += (ne > nrm) || (ne == nrm && e < lane);
    }

    // ut[mat][rank][row] = g[row]/sigma
    const float inv = __builtin_amdgcn_rsqf(fmaxf(nrm, 1e-30f));
    float* dst = ut + (mat * 64 + rank) * 64 + row0;
    #pragma unroll
    for (int i = 0; i < 16; i++) dst[i] = g[i] * inv;
}

// ---------------- Kernel 2: spd accumulation (LDS-return-BW bound, ~72 us) ----------------
__global__ __launch_bounds__(256) void spd_kernel(const float* __restrict__ D,
                                                  const float* __restrict__ w,
                                                  const float* __restrict__ ut,
                                                  float* __restrict__ out) {
    __shared__ __align__(16) float U[64][64];   // U[d][i]
    __shared__ float t[64];

    const int bid = blockIdx.x;
    const int b = bid >> 4, o = bid & 15;
    const int tid = threadIdx.x;
    const int ti = tid & 15, tj = tid >> 4;

    float acc[4][4] = {{0.f, 0.f, 0.f, 0.f}, {0.f, 0.f, 0.f, 0.f},
                       {0.f, 0.f, 0.f, 0.f}, {0.f, 0.f, 0.f, 0.f}};

    for (int cn = 0; cn < 16; cn++) {
        __syncthreads();   // protect U/t from previous iteration's readers
        const float4* src = (const float4*)(ut + cn * 4096);
        float4* dstU = (float4*)(&U[0][0]);
        #pragma unroll
        for (int idx = tid; idx < 1024; idx += 256) dstU[idx] = src[idx];
        if (tid < 64) {
            int d = tid;
            float dv = D[(b * 16 + cn) * 64 + d];
            float wv = fabsf(w[(d * 16 + cn) * 16 + o]);
            t[d] = dv * wv;
        }
        __syncthreads();

        #pragma unroll 4
        for (int d = 0; d < 64; d++) {
            float td = t[d];
            float4 uiv = *(const float4*)(&U[d][ti * 4]);
            float4 ujv = *(const float4*)(&U[d][tj * 4]);
            float si0 = td * uiv.x, si1 = td * uiv.y, si2 = td * uiv.z, si3 = td * uiv.w;
            acc[0][0] += si0 * ujv.x; acc[0][1] += si0 * ujv.y; acc[0][2] += si0 * ujv.z; acc[0][3] += si0 * ujv.w;
            acc[1][0] += si1 * ujv.x; acc[1][1] += si1 * ujv.y; acc[1][2] += si1 * ujv.z; acc[1][3] += si1 * ujv.w;
            acc[2][0] += si2 * ujv.x; acc[2][1] += si2 * ujv.y; acc[2][2] += si2 * ujv.z; acc[2][3] += si2 * ujv.w;
            acc[3][0] += si3 * ujv.x; acc[3][1] += si3 * ujv.y; acc[3][2] += si3 * ujv.z; acc[3][3] += si3 * ujv.w;
        }
    }

    float* obase = out + (size_t)bid * 4096;
    #pragma unroll
    for (int k = 0; k < 4; k++) {
        float4 v = make_float4(acc[k][0], acc[k][1], acc[k][2], acc[k][3]);
        *(float4*)(&obase[(ti * 4 + k) * 64 + tj * 4]) = v;
    }
}

extern "C" void kernel_launch(void* const* d_in, const int* in_sizes, int n_in,
                              void* d_out, int out_size, void* d_ws, size_t ws_size,
                              hipStream_t stream) {
    const float* D = (const float*)d_in[0];   // (32,2,8,64)
    const float* C = (const float*)d_in[1];   // (2,8,64,64)
    const float* w = (const float*)d_in[2];   // (64,2,8,16)
    float* out = (float*)d_out;               // (32,16,64,64)
    float* ut  = (float*)d_ws;                // 16*64*64 floats = 256 KB

    hipLaunchKernelGGL(eig_kernel, dim3(16), dim3(256), 0, stream, C, ut);
    hipLaunchKernelGGL(spd_kernel, dim3(512), dim3(256), 0, stream, D, w, ut, out);
}